// Round 4
// baseline (828.970 us; speedup 1.0000x reference)
//
#include <hip/hip_runtime.h>

// GCN layer, atomic-free binned pull:
//   segment_sum(x@W^T)[dst] == segment_sum(x)[dst] @ W^T  (linearity)
// Pipeline (no global atomics anywhere):
//   0) convert x -> bf16 (halves random-gather bytes; fp32 accumulate)
//   1) bin_count: per-block LDS hist over NB buckets (128 nodes each)
//      -> bhistT[bucket*BLK1 + block]
//   2) 3-pass scan of bhistT (M = NB*BLK1 entries) -> scanT (+ total at [M])
//   3) bin_scatter: LDS cursors from scanT; write packed (src<<7 | dstlo)
//   4) accum_transform: block per bucket; 32KB LDS fp32 acc[128][64];
//      8 edges/wave-iter, wave-uniform src (readlane) -> scalar-base row
//      loads; ds_add_f32 accumulate; epilogue: row @ W^T + bias -> out.
// Fallback tiers if ws too small: fp32 gather (no xb), then atomic scatter.

#define DIM 64
#define BN 128            // nodes per bucket
#define BN_SHIFT 7
#define BN_MASK 127
#define NB_MAX 1024
#define BLK1 512          // binning blocks
#define SCAN_BLOCKS 256

__device__ __forceinline__ unsigned short f32_to_bf16_rne(float f) {
    unsigned u = __float_as_uint(f);
    unsigned r = u + 0x7FFFu + ((u >> 16) & 1u);
    return (unsigned short)(r >> 16);
}

// ---------------------------------------------------------------------------
__global__ void convert_bf16_kernel(const float* __restrict__ x,
                                    ushort4* __restrict__ xb4, int total4) {
    int i = blockIdx.x * blockDim.x + threadIdx.x;
    if (i >= total4) return;
    float4 v = ((const float4*)x)[i];
    ushort4 o;
    o.x = f32_to_bf16_rne(v.x); o.y = f32_to_bf16_rne(v.y);
    o.z = f32_to_bf16_rne(v.z); o.w = f32_to_bf16_rne(v.w);
    xb4[i] = o;
}

// ---------------------------------------------------------------------------
__global__ __launch_bounds__(256) void bin_count_kernel(
        const int* __restrict__ ei, int* __restrict__ bhistT, int E, int nb) {
    __shared__ int h[NB_MAX];
    int t = threadIdx.x;
    for (int b = t; b < nb; b += 256) h[b] = 0;
    __syncthreads();
    for (int e = blockIdx.x * 256 + t; e < E; e += BLK1 * 256)
        atomicAdd(&h[ei[E + e] >> BN_SHIFT], 1);
    __syncthreads();
    for (int b = t; b < nb; b += 256)
        bhistT[b * BLK1 + blockIdx.x] = h[b];
}

// --------------------------- 3-pass scan -----------------------------------
__global__ void scan_reduce_kernel(const int* __restrict__ in,
                                   int* __restrict__ bsum, int n, int chunk) {
    __shared__ int ws[4];
    int b = blockIdx.x, t = threadIdx.x;
    int base = b * chunk;
    int lim = min(base + chunk, n);
    int sum = 0;
    for (int i = base + t; i < lim; i += 256) sum += in[i];
    #pragma unroll
    for (int d = 32; d; d >>= 1) sum += __shfl_down(sum, d, 64);
    if ((t & 63) == 0) ws[t >> 6] = sum;
    __syncthreads();
    if (t == 0) bsum[b] = ws[0] + ws[1] + ws[2] + ws[3];
}

__global__ void scan_partials_kernel(const int* __restrict__ bsum,
                                     int* __restrict__ bpre,
                                     int* __restrict__ outp, int n) {
    __shared__ int tmp[SCAN_BLOCKS];
    int t = threadIdx.x;
    int v = bsum[t];
    tmp[t] = v;
    __syncthreads();
    #pragma unroll
    for (int d = 1; d < SCAN_BLOCKS; d <<= 1) {
        int u = (t >= d) ? tmp[t - d] : 0;
        __syncthreads();
        tmp[t] += u;
        __syncthreads();
    }
    bpre[t] = tmp[t] - v;
    if (t == SCAN_BLOCKS - 1) outp[n] = tmp[t];   // total
}

__global__ void scan_write_kernel(const int* __restrict__ in,
                                  const int* __restrict__ bpre,
                                  int* __restrict__ outp, int n, int chunk) {
    __shared__ int tmp[256];
    int b = blockIdx.x, t = threadIdx.x;
    int base = b * chunk;
    int lim = min(base + chunk, n);
    int carry = bpre[b];
    for (int tile = base; tile < lim; tile += 256) {
        int i = tile + t;
        int v = (i < lim) ? in[i] : 0;
        tmp[t] = v;
        __syncthreads();
        #pragma unroll
        for (int d = 1; d < 256; d <<= 1) {
            int u = (t >= d) ? tmp[t - d] : 0;
            __syncthreads();
            tmp[t] += u;
            __syncthreads();
        }
        if (i < lim) outp[i] = carry + (tmp[t] - v);
        int total = tmp[255];
        __syncthreads();
        carry += total;
    }
}

// ---------------------------------------------------------------------------
__global__ __launch_bounds__(256) void bin_scatter_kernel(
        const int* __restrict__ ei, const int* __restrict__ scanT,
        int* __restrict__ binned, int E, int nb) {
    __shared__ int cur[NB_MAX];
    int t = threadIdx.x;
    for (int b = t; b < nb; b += 256) cur[b] = scanT[b * BLK1 + blockIdx.x];
    __syncthreads();
    for (int e = blockIdx.x * 256 + t; e < E; e += BLK1 * 256) {
        int s = ei[e];
        int d = ei[E + e];
        int p = atomicAdd(&cur[d >> BN_SHIFT], 1);
        binned[p] = (s << BN_SHIFT) | (d & BN_MASK);
    }
}

// ---------------------------------------------------------------------------
template <bool USE_BF16>
__global__ __launch_bounds__(256) void accum_transform_kernel(
        const void* __restrict__ xsrc, const int* __restrict__ scanT,
        const int* __restrict__ binned, const float* __restrict__ W,
        const float* __restrict__ bias, float* __restrict__ out,
        int N, int nb) {
    __shared__ float acc[BN][DIM];        // 32 KB
    const int t = threadIdx.x;
    const int lane = t & 63;
    const int wid = t >> 6;               // 0..3
    const int b = blockIdx.x;

    // zero accumulator
    float4* af4 = (float4*)acc;
    #pragma unroll
    for (int i = t; i < BN * DIM / 4; i += 256)
        af4[i] = make_float4(0.f, 0.f, 0.f, 0.f);

    const int start = scanT[b * BLK1];
    const int end   = scanT[(b + 1) * BLK1];
    __syncthreads();

    // edge loop: each wave takes 8 edges per iteration
    for (int i = start + wid * 8; i < end; i += 4 * 8) {
        int m = min(8, end - i);
        int li = i + (lane & 7);
        int v = (li < end) ? binned[li] : 0;
        if (m == 8) {
            #pragma unroll
            for (int j = 0; j < 8; ++j) {
                int pk = __builtin_amdgcn_readlane(v, j);
                int s  = pk >> BN_SHIFT;
                int nl = pk & BN_MASK;
                float xv;
                if (USE_BF16) {
                    unsigned short h =
                        ((const unsigned short*)xsrc)[(size_t)s * DIM + lane];
                    xv = __uint_as_float(((unsigned)h) << 16);
                } else {
                    xv = ((const float*)xsrc)[(size_t)s * DIM + lane];
                }
                unsafeAtomicAdd(&acc[nl][lane], xv);
            }
        } else {
            for (int j = 0; j < m; ++j) {
                int pk = __builtin_amdgcn_readlane(v, j);
                int s  = pk >> BN_SHIFT;
                int nl = pk & BN_MASK;
                float xv;
                if (USE_BF16) {
                    unsigned short h =
                        ((const unsigned short*)xsrc)[(size_t)s * DIM + lane];
                    xv = __uint_as_float(((unsigned)h) << 16);
                } else {
                    xv = ((const float*)xsrc)[(size_t)s * DIM + lane];
                }
                unsafeAtomicAdd(&acc[nl][lane], xv);
            }
        }
    }

    // W row `lane` into regs + bias
    float wv[DIM];
    #pragma unroll
    for (int k4 = 0; k4 < DIM / 4; ++k4) {
        float4 tw = *(const float4*)(W + (size_t)lane * DIM + k4 * 4);
        wv[k4 * 4 + 0] = tw.x; wv[k4 * 4 + 1] = tw.y;
        wv[k4 * 4 + 2] = tw.z; wv[k4 * 4 + 3] = tw.w;
    }
    const float bb = bias[lane];
    __syncthreads();

    const int node0 = b * BN;
    const int nloc = min(BN, N - node0);
    for (int n = wid; n < nloc; n += 4) {
        float a = acc[n][lane];
        float r0 = bb, r1 = 0.f, r2 = 0.f, r3 = 0.f;
        #pragma unroll
        for (int k = 0; k < DIM; k += 4) {
            r0 += __int_as_float(__builtin_amdgcn_readlane(__float_as_int(a), k + 0)) * wv[k + 0];
            r1 += __int_as_float(__builtin_amdgcn_readlane(__float_as_int(a), k + 1)) * wv[k + 1];
            r2 += __int_as_float(__builtin_amdgcn_readlane(__float_as_int(a), k + 2)) * wv[k + 2];
            r3 += __int_as_float(__builtin_amdgcn_readlane(__float_as_int(a), k + 3)) * wv[k + 3];
        }
        out[(size_t)(node0 + n) * DIM + lane] = (r0 + r1) + (r2 + r3);
    }
}

// --------------------- fallback: atomic scatter path -----------------------
__global__ void gcn_scatter_kernel(const float* __restrict__ x,
                                   const int* __restrict__ edge_index,
                                   float* __restrict__ out, int n_edges) {
    int gid = blockIdx.x * blockDim.x + threadIdx.x;
    int e = gid >> 4;
    if (e >= n_edges) return;
    int j = (gid & 15) << 2;
    int src = edge_index[e];
    int dst = edge_index[n_edges + e];
    const float4 v = *(const float4*)(x + (size_t)src * DIM + j);
    float* o = out + (size_t)dst * DIM + j;
    atomicAdd(o + 0, v.x); atomicAdd(o + 1, v.y);
    atomicAdd(o + 2, v.z); atomicAdd(o + 3, v.w);
}

__global__ void gcn_linear_inplace_kernel(float* __restrict__ out,
                                          const float* __restrict__ W,
                                          const float* __restrict__ bias,
                                          int n_nodes) {
    __shared__ float Wt[DIM * DIM];
    __shared__ float rows[4][DIM];
    int tid = threadIdx.x;
    int col = tid & 63;
    int r = tid >> 6;
    for (int i = tid; i < DIM * DIM; i += 256) {
        int c = i >> 6, k = i & 63;
        Wt[k * DIM + c] = W[i];
    }
    int row = blockIdx.x * 4 + r;
    if (row < n_nodes) rows[r][col] = out[(size_t)row * DIM + col];
    __syncthreads();
    if (row < n_nodes) {
        float a = 0.f;
        #pragma unroll
        for (int k = 0; k < DIM; ++k) a += rows[r][k] * Wt[k * DIM + col];
        out[(size_t)row * DIM + col] = a + bias[col];
    }
}

// ---------------------------------------------------------------------------
extern "C" void kernel_launch(void* const* d_in, const int* in_sizes, int n_in,
                              void* d_out, int out_size, void* d_ws, size_t ws_size,
                              hipStream_t stream) {
    const float* x          = (const float*)d_in[0];   // [N, 64]
    const float* W          = (const float*)d_in[1];   // [64, 64]
    const float* bias       = (const float*)d_in[2];   // [64]
    const int*   edge_index = (const int*)d_in[3];     // [2, E]

    const int E = in_sizes[3] / 2;
    const int N = in_sizes[0] / DIM;
    float* out = (float*)d_out;

    const int NB = (N + BN - 1) >> BN_SHIFT;
    const long long M = (long long)NB * BLK1;

    // workspace layout (256B-aligned chunks)
    auto align256 = [](size_t v) { return (v + 255) & ~(size_t)255; };
    size_t off = 0;
    size_t xb_off     = off; off += align256((size_t)N * DIM * 2);
    size_t binned_off = off; off += align256((size_t)E * 4);
    size_t hist_off   = off; off += align256((size_t)M * 4);
    size_t scan_off   = off; off += align256(((size_t)M + 1) * 4);
    size_t bsum_off   = off; off += align256(SCAN_BLOCKS * 4);
    size_t bpre_off   = off; off += align256(SCAN_BLOCKS * 4);
    const size_t need_bf16 = off;
    const size_t need_fp32 = off - align256((size_t)N * DIM * 2);

    const bool fits_bf16 = (ws_size >= need_bf16) && (NB <= NB_MAX);
    const bool fits_fp32 = (ws_size >= need_fp32) && (NB <= NB_MAX);

    if (fits_bf16 || fits_fp32) {
        char* base = (char*)d_ws;
        // if no room for xb, shift layout down by the xb chunk
        size_t shift = fits_bf16 ? 0 : align256((size_t)N * DIM * 2);
        ushort4* xb4 = (ushort4*)(base + xb_off);
        int* binned  = (int*)(base + binned_off - shift);
        int* bhistT  = (int*)(base + hist_off - shift);
        int* scanT   = (int*)(base + scan_off - shift);
        int* bsum    = (int*)(base + bsum_off - shift);
        int* bpre    = (int*)(base + bpre_off - shift);

        const int block = 256;
        const int chunkM = (int)((M + SCAN_BLOCKS - 1) / SCAN_BLOCKS);

        if (fits_bf16) {
            int total4 = N * DIM / 4;
            convert_bf16_kernel<<<(total4 + block - 1) / block, block, 0, stream>>>(
                x, xb4, total4);
        }
        bin_count_kernel<<<BLK1, block, 0, stream>>>(edge_index, bhistT, E, NB);
        scan_reduce_kernel<<<SCAN_BLOCKS, block, 0, stream>>>(bhistT, bsum, (int)M, chunkM);
        scan_partials_kernel<<<1, SCAN_BLOCKS, 0, stream>>>(bsum, bpre, scanT, (int)M);
        scan_write_kernel<<<SCAN_BLOCKS, block, 0, stream>>>(bhistT, bpre, scanT, (int)M, chunkM);
        bin_scatter_kernel<<<BLK1, block, 0, stream>>>(edge_index, scanT, binned, E, NB);

        if (fits_bf16) {
            accum_transform_kernel<true><<<NB, block, 0, stream>>>(
                (const void*)xb4, scanT, binned, W, bias, out, N, NB);
        } else {
            accum_transform_kernel<false><<<NB, block, 0, stream>>>(
                (const void*)x, scanT, binned, W, bias, out, N, NB);
        }
    } else {
        // atomic fallback
        hipMemsetAsync(d_out, 0, (size_t)out_size * sizeof(float), stream);
        long long total = (long long)E * 16;
        int block = 256;
        int grid = (int)((total + block - 1) / block);
        gcn_scatter_kernel<<<grid, block, 0, stream>>>(x, edge_index, out, E);
        int lgrid = (N + 3) / 4;
        gcn_linear_inplace_kernel<<<lgrid, 256, 0, stream>>>(out, W, bias, N);
    }
}

// Round 5
// 272.529 us; speedup vs baseline: 3.0418x; 3.0418x over previous
//
#include <hip/hip_runtime.h>

// GCN layer: segment_sum(x@W^T)[dst] == segment_sum(x)[dst] @ W^T (linearity).
// Round-5 pipeline (zero global atomics on the fast path):
//   0) convert x -> bf16 (halves random-gather bytes)
//   1) bin_count: LDS hist over NB=ceil(N/128) buckets -> bhistT[bkt*BLK1+blk]
//   2) 3-pass parallel scan of bhistT -> scanT (+ total at [M])
//   3) bin_scatter: LDS cursors; binned[p] = (src<<7)|(dst&127)
//   4) bucket_sort: block per bucket; 128 LDS counters; exact CSR
//      (offsets[node], srcs[] grouped by node) - all traffic L2-local
//   5) gather_linear (round-3 structure): wave per ~8 nodes, lane=feature,
//      8-wide edge unroll, bf16 row loads, W row per lane, readlane epilogue
// Tiers: A bf16+binned, B fp32+binned, C round-3 (global-atomic CSR), D atomic.

#define DIM 64
#define BN 128
#define BN_SHIFT 7
#define BN_MASK 127
#define NB_MAX 1024
#define BLK1 512
#define SCAN_BLOCKS 256

__device__ __forceinline__ unsigned short f32_to_bf16_rne(float f) {
    unsigned u = __float_as_uint(f);
    unsigned r = u + 0x7FFFu + ((u >> 16) & 1u);
    return (unsigned short)(r >> 16);
}

// ---------------------------------------------------------------------------
__global__ void convert_bf16_kernel(const float* __restrict__ x,
                                    ushort4* __restrict__ xb4, int total4) {
    int i = blockIdx.x * blockDim.x + threadIdx.x;
    if (i >= total4) return;
    float4 v = ((const float4*)x)[i];
    ushort4 o;
    o.x = f32_to_bf16_rne(v.x); o.y = f32_to_bf16_rne(v.y);
    o.z = f32_to_bf16_rne(v.z); o.w = f32_to_bf16_rne(v.w);
    xb4[i] = o;
}

// ---------------------------------------------------------------------------
__global__ __launch_bounds__(256) void bin_count_kernel(
        const int* __restrict__ ei, int* __restrict__ bhistT, int E, int nb) {
    __shared__ int h[NB_MAX];
    int t = threadIdx.x;
    for (int b = t; b < nb; b += 256) h[b] = 0;
    __syncthreads();
    for (int e = blockIdx.x * 256 + t; e < E; e += BLK1 * 256)
        atomicAdd(&h[ei[E + e] >> BN_SHIFT], 1);
    __syncthreads();
    for (int b = t; b < nb; b += 256)
        bhistT[b * BLK1 + blockIdx.x] = h[b];
}

// --------------------------- 3-pass scan -----------------------------------
__global__ void scan_reduce_kernel(const int* __restrict__ in,
                                   int* __restrict__ bsum, int n, int chunk) {
    __shared__ int ws[4];
    int b = blockIdx.x, t = threadIdx.x;
    int base = b * chunk;
    int lim = min(base + chunk, n);
    int sum = 0;
    for (int i = base + t; i < lim; i += 256) sum += in[i];
    #pragma unroll
    for (int d = 32; d; d >>= 1) sum += __shfl_down(sum, d, 64);
    if ((t & 63) == 0) ws[t >> 6] = sum;
    __syncthreads();
    if (t == 0) bsum[b] = ws[0] + ws[1] + ws[2] + ws[3];
}

__global__ void scan_partials_kernel(const int* __restrict__ bsum,
                                     int* __restrict__ bpre,
                                     int* __restrict__ outp, int n) {
    __shared__ int tmp[SCAN_BLOCKS];
    int t = threadIdx.x;
    int v = bsum[t];
    tmp[t] = v;
    __syncthreads();
    #pragma unroll
    for (int d = 1; d < SCAN_BLOCKS; d <<= 1) {
        int u = (t >= d) ? tmp[t - d] : 0;
        __syncthreads();
        tmp[t] += u;
        __syncthreads();
    }
    bpre[t] = tmp[t] - v;
    if (t == SCAN_BLOCKS - 1) outp[n] = tmp[t];   // total
}

__global__ void scan_write_kernel(const int* __restrict__ in,
                                  const int* __restrict__ bpre,
                                  int* __restrict__ outp, int n, int chunk) {
    __shared__ int tmp[256];
    int b = blockIdx.x, t = threadIdx.x;
    int base = b * chunk;
    int lim = min(base + chunk, n);
    int carry = bpre[b];
    for (int tile = base; tile < lim; tile += 256) {
        int i = tile + t;
        int v = (i < lim) ? in[i] : 0;
        tmp[t] = v;
        __syncthreads();
        #pragma unroll
        for (int d = 1; d < 256; d <<= 1) {
            int u = (t >= d) ? tmp[t - d] : 0;
            __syncthreads();
            tmp[t] += u;
            __syncthreads();
        }
        if (i < lim) outp[i] = carry + (tmp[t] - v);
        int total = tmp[255];
        __syncthreads();
        carry += total;
    }
}

// ---------------------------------------------------------------------------
__global__ __launch_bounds__(256) void bin_scatter_kernel(
        const int* __restrict__ ei, const int* __restrict__ scanT,
        int* __restrict__ binned, int E, int nb) {
    __shared__ int cur[NB_MAX];
    int t = threadIdx.x;
    for (int b = t; b < nb; b += 256) cur[b] = scanT[b * BLK1 + blockIdx.x];
    __syncthreads();
    for (int e = blockIdx.x * 256 + t; e < E; e += BLK1 * 256) {
        int s = ei[e];
        int d = ei[E + e];
        int p = atomicAdd(&cur[d >> BN_SHIFT], 1);
        binned[p] = (s << BN_SHIFT) | (d & BN_MASK);
    }
}

// ---------------------------------------------------------------------------
// Block per bucket: counting sort by low-7 dst bits -> exact CSR.
__global__ __launch_bounds__(256) void bucket_sort_kernel(
        const int* __restrict__ binned, const int* __restrict__ scanT,
        int* __restrict__ srcs, int* __restrict__ offsets, int N, int nb) {
    __shared__ int cnt[BN];
    __shared__ int base[BN];
    const int t = threadIdx.x;
    const int b = blockIdx.x;
    const int seg0 = scanT[b * BLK1];
    const int seg1 = scanT[(b + 1) * BLK1];   // b=nb-1 hits scanT[M]=total

    if (t < BN) cnt[t] = 0;
    __syncthreads();
    for (int i = seg0 + t; i < seg1; i += 256)
        atomicAdd(&cnt[binned[i] & BN_MASK], 1);
    __syncthreads();
    if (t == 0) {
        int run = 0;
        #pragma unroll 8
        for (int j = 0; j < BN; ++j) { base[j] = run; run += cnt[j]; }
    }
    __syncthreads();
    const int node0 = b << BN_SHIFT;
    if (t < BN && node0 + t < N) offsets[node0 + t] = seg0 + base[t];
    if (b == 0 && t == 0) offsets[N] = scanT[(size_t)nb * BLK1];
    if (t < BN) cnt[t] = base[t];             // reuse as cursor
    __syncthreads();
    for (int i = seg0 + t; i < seg1; i += 256) {
        int v = binned[i];                    // L2-hot re-read
        int p = atomicAdd(&cnt[v & BN_MASK], 1);
        srcs[seg0 + p] = v >> BN_SHIFT;
    }
}

// ---------------------------------------------------------------------------
// Wave per ~8 nodes; lane = feature; 8-wide edge unroll; readlane epilogue.
template <bool BF16>
__global__ __launch_bounds__(256) void gather_linear_kernel(
        const void* __restrict__ xsrc, const int* __restrict__ offsets,
        const int* __restrict__ srcs, const float* __restrict__ W,
        const float* __restrict__ bias, float* __restrict__ out, int n_nodes) {
    const int lane = threadIdx.x & 63;
    const int gwave = (blockIdx.x * blockDim.x + threadIdx.x) >> 6;
    const int total_waves = (gridDim.x * blockDim.x) >> 6;

    const unsigned short* xh = (const unsigned short*)xsrc;
    const float* xf = (const float*)xsrc;
    #define LDX(s) (BF16 ? __uint_as_float((unsigned)xh[(size_t)(s) * DIM + lane] << 16) \
                         : xf[(size_t)(s) * DIM + lane])

    float wv[DIM];
    #pragma unroll
    for (int k4 = 0; k4 < DIM / 4; ++k4) {
        float4 tw = *(const float4*)(W + (size_t)lane * DIM + k4 * 4);
        wv[k4 * 4 + 0] = tw.x; wv[k4 * 4 + 1] = tw.y;
        wv[k4 * 4 + 2] = tw.z; wv[k4 * 4 + 3] = tw.w;
    }
    const float b = bias[lane];

    for (int node = gwave; node < n_nodes; node += total_waves) {
        int beg = offsets[node];
        int end = offsets[node + 1];

        float a0 = 0.f, a1 = 0.f, a2 = 0.f, a3 = 0.f;
        float a4 = 0.f, a5 = 0.f, a6 = 0.f, a7 = 0.f;
        int i = beg;
        for (; i + 8 <= end; i += 8) {
            int s0 = srcs[i + 0], s1 = srcs[i + 1];
            int s2 = srcs[i + 2], s3 = srcs[i + 3];
            int s4 = srcs[i + 4], s5 = srcs[i + 5];
            int s6 = srcs[i + 6], s7 = srcs[i + 7];
            a0 += LDX(s0); a1 += LDX(s1); a2 += LDX(s2); a3 += LDX(s3);
            a4 += LDX(s4); a5 += LDX(s5); a6 += LDX(s6); a7 += LDX(s7);
        }
        if (i + 4 <= end) {
            int s0 = srcs[i + 0], s1 = srcs[i + 1];
            int s2 = srcs[i + 2], s3 = srcs[i + 3];
            a0 += LDX(s0); a1 += LDX(s1); a2 += LDX(s2); a3 += LDX(s3);
            i += 4;
        }
        for (; i < end; ++i) a0 += LDX(srcs[i]);
        float acc = ((a0 + a1) + (a2 + a3)) + ((a4 + a5) + (a6 + a7));

        float r0 = b, r1 = 0.f, r2 = 0.f, r3 = 0.f;
        #pragma unroll
        for (int k = 0; k < DIM; k += 4) {
            r0 += __int_as_float(__builtin_amdgcn_readlane(__float_as_int(acc), k + 0)) * wv[k + 0];
            r1 += __int_as_float(__builtin_amdgcn_readlane(__float_as_int(acc), k + 1)) * wv[k + 1];
            r2 += __int_as_float(__builtin_amdgcn_readlane(__float_as_int(acc), k + 2)) * wv[k + 2];
            r3 += __int_as_float(__builtin_amdgcn_readlane(__float_as_int(acc), k + 3)) * wv[k + 3];
        }
        out[(size_t)node * DIM + lane] = (r0 + r1) + (r2 + r3);
    }
    #undef LDX
}

// ------------------- tier C: global-atomic CSR build -----------------------
__global__ void hist_kernel(const int* __restrict__ ei, int* __restrict__ counts,
                            int E) {
    int e = blockIdx.x * blockDim.x + threadIdx.x;
    if (e < E) atomicAdd(&counts[ei[E + e]], 1);
}

__global__ void copy_kernel(const int* __restrict__ src, int* __restrict__ dst,
                            int n) {
    int i = blockIdx.x * blockDim.x + threadIdx.x;
    if (i < n) dst[i] = src[i];
}

__global__ void fill_kernel(const int* __restrict__ ei, int* __restrict__ cursor,
                            int* __restrict__ srcs, int E) {
    int e = blockIdx.x * blockDim.x + threadIdx.x;
    if (e < E) {
        int d = ei[E + e];
        int p = atomicAdd(&cursor[d], 1);
        srcs[p] = ei[e];
    }
}

// ------------------- tier D: atomic scatter fallback -----------------------
__global__ void gcn_scatter_kernel(const float* __restrict__ x,
                                   const int* __restrict__ edge_index,
                                   float* __restrict__ out, int n_edges) {
    int gid = blockIdx.x * blockDim.x + threadIdx.x;
    int e = gid >> 4;
    if (e >= n_edges) return;
    int j = (gid & 15) << 2;
    int src = edge_index[e];
    int dst = edge_index[n_edges + e];
    const float4 v = *(const float4*)(x + (size_t)src * DIM + j);
    float* o = out + (size_t)dst * DIM + j;
    atomicAdd(o + 0, v.x); atomicAdd(o + 1, v.y);
    atomicAdd(o + 2, v.z); atomicAdd(o + 3, v.w);
}

__global__ void gcn_linear_inplace_kernel(float* __restrict__ out,
                                          const float* __restrict__ W,
                                          const float* __restrict__ bias,
                                          int n_nodes) {
    __shared__ float Wt[DIM * DIM];
    __shared__ float rows[4][DIM];
    int tid = threadIdx.x;
    int col = tid & 63;
    int r = tid >> 6;
    for (int i = tid; i < DIM * DIM; i += 256) {
        int c = i >> 6, k = i & 63;
        Wt[k * DIM + c] = W[i];
    }
    int row = blockIdx.x * 4 + r;
    if (row < n_nodes) rows[r][col] = out[(size_t)row * DIM + col];
    __syncthreads();
    if (row < n_nodes) {
        float a = 0.f;
        #pragma unroll
        for (int k = 0; k < DIM; ++k) a += rows[r][k] * Wt[k * DIM + col];
        out[(size_t)row * DIM + col] = a + bias[col];
    }
}

// ---------------------------------------------------------------------------
extern "C" void kernel_launch(void* const* d_in, const int* in_sizes, int n_in,
                              void* d_out, int out_size, void* d_ws, size_t ws_size,
                              hipStream_t stream) {
    const float* x          = (const float*)d_in[0];   // [N, 64]
    const float* W          = (const float*)d_in[1];   // [64, 64]
    const float* bias       = (const float*)d_in[2];   // [64]
    const int*   edge_index = (const int*)d_in[3];     // [2, E]

    const int E = in_sizes[3] / 2;
    const int N = in_sizes[0] / DIM;
    float* out = (float*)d_out;

    const int NB = (N + BN - 1) >> BN_SHIFT;
    const long long M = (long long)NB * BLK1;
    const int block = 256;

    auto align256 = [](size_t v) { return (v + 255) & ~(size_t)255; };
    const size_t xb_b   = align256((size_t)N * DIM * 2);
    const size_t bin_b  = align256((size_t)E * 4);
    const size_t hist_b = align256((size_t)M * 4);
    const size_t scan_b = align256(((size_t)M + 1) * 4);
    const size_t srcs_b = align256((size_t)E * 4);
    const size_t offs_b = align256(((size_t)N + 1) * 4);
    const size_t sm_b   = align256(SCAN_BLOCKS * 4);
    const size_t needB = bin_b + hist_b + scan_b + srcs_b + offs_b + 2 * sm_b;
    const size_t needA = needB + xb_b;
    const size_t needC = ((size_t)3 * N + 1 + E) * sizeof(int);

    if (NB <= NB_MAX && ws_size >= needB) {
        const bool bf16 = (ws_size >= needA);
        char* p = (char*)d_ws;
        ushort4* xb4 = (ushort4*)p;          if (bf16) p += xb_b;
        int* binned  = (int*)p;              p += bin_b;
        int* bhistT  = (int*)p;              p += hist_b;
        int* scanT   = (int*)p;              p += scan_b;
        int* srcs    = (int*)p;              p += srcs_b;
        int* offsets = (int*)p;              p += offs_b;
        int* bsum    = (int*)p;              p += sm_b;
        int* bpre    = (int*)p;

        const int chunkM = (int)((M + SCAN_BLOCKS - 1) / SCAN_BLOCKS);

        if (bf16) {
            int total4 = N * DIM / 4;
            convert_bf16_kernel<<<(total4 + block - 1) / block, block, 0, stream>>>(
                x, xb4, total4);
        }
        bin_count_kernel<<<BLK1, block, 0, stream>>>(edge_index, bhistT, E, NB);
        scan_reduce_kernel<<<SCAN_BLOCKS, block, 0, stream>>>(bhistT, bsum, (int)M, chunkM);
        scan_partials_kernel<<<1, SCAN_BLOCKS, 0, stream>>>(bsum, bpre, scanT, (int)M);
        scan_write_kernel<<<SCAN_BLOCKS, block, 0, stream>>>(bhistT, bpre, scanT, (int)M, chunkM);
        bin_scatter_kernel<<<BLK1, block, 0, stream>>>(edge_index, scanT, binned, E, NB);
        bucket_sort_kernel<<<NB, block, 0, stream>>>(binned, scanT, srcs, offsets, N, NB);

        int waves = (N + 7) / 8;
        int ggrid = (waves + 3) / 4;
        if (bf16)
            gather_linear_kernel<true><<<ggrid, block, 0, stream>>>(
                (const void*)xb4, offsets, srcs, W, bias, out, N);
        else
            gather_linear_kernel<false><<<ggrid, block, 0, stream>>>(
                (const void*)x, offsets, srcs, W, bias, out, N);
    } else if (ws_size >= needC) {
        int* counts  = (int*)d_ws;
        int* offsets = counts + N;
        int* cursor  = offsets + N + 1;
        int* srcs    = cursor + N;
        int* bsum    = srcs + E;              // small, reuse tail if present
        int* bpre    = bsum + SCAN_BLOCKS;

        hipMemsetAsync(counts, 0, (size_t)N * sizeof(int), stream);
        const int egrid = (E + block - 1) / block;
        const int chunkN = (N + SCAN_BLOCKS - 1) / SCAN_BLOCKS;
        hist_kernel<<<egrid, block, 0, stream>>>(edge_index, counts, E);
        scan_reduce_kernel<<<SCAN_BLOCKS, block, 0, stream>>>(counts, bsum, N, chunkN);
        scan_partials_kernel<<<1, SCAN_BLOCKS, 0, stream>>>(bsum, bpre, offsets, N);
        scan_write_kernel<<<SCAN_BLOCKS, block, 0, stream>>>(counts, bpre, offsets, N, chunkN);
        copy_kernel<<<(N + block - 1) / block, block, 0, stream>>>(offsets, cursor, N);
        fill_kernel<<<egrid, block, 0, stream>>>(edge_index, cursor, srcs, E);
        int waves = (N + 7) / 8;
        int ggrid = (waves + 3) / 4;
        gather_linear_kernel<false><<<ggrid, block, 0, stream>>>(
            (const void*)x, offsets, srcs, W, bias, out, N);
    } else {
        hipMemsetAsync(d_out, 0, (size_t)out_size * sizeof(float), stream);
        long long total = (long long)E * 16;
        int grid = (int)((total + block - 1) / block);
        gcn_scatter_kernel<<<grid, block, 0, stream>>>(x, edge_index, out, E);
        int lgrid = (N + 3) / 4;
        gcn_linear_inplace_kernel<<<lgrid, 256, 0, stream>>>(out, W, bias, N);
    }
}

// Round 6
// 244.318 us; speedup vs baseline: 3.3930x; 1.1155x over previous
//
#include <hip/hip_runtime.h>

// GCN layer: segment_sum(x@W^T)[dst] == segment_sum(x)[dst] @ W^T (linearity).
// Round-6 pipeline (zero global atomics on fast path):
//   0) convert x -> bf16
//   1) bin_count: LDS hist over NB=ceil(N/1024) buckets -> bhistT[bkt*BLK1+blk]
//   2) 3-pass parallel scan of bhistT -> scanT  (per-block per-bucket bases;
//      runs of ~32 edges = 128B => bin_scatter writes are full-line)
//   3) bin_scatter: LDS cursors; binned[p] = (src<<10)|(dst&1023)
//   4) bucket_sort: block per bucket; 1024 LDS counters + parallel prefix;
//      exact CSR (offsets, srcs) — scatter stays inside a 64KB L2 window
//   5) gather_linear_bf16: wave per ~8 nodes; 8 lanes/edge x 16B dwordx4
//      (8 edges per load inst); shfl_xor group-reduce; readlane @ W^T epilogue
// Tiers: A bf16+binned, B fp32 scalar gather + binned CSR impossible here ->
//        B uses global-atomic CSR, D atomic scatter.

#define DIM 64
#define BN 1024           // nodes per bucket
#define BN_SHIFT 10
#define BN_MASK 1023
#define NB_HIST_MAX 128   // LDS hist/cursor capacity (NB=98 for N=100K)
#define BLK1 512          // binning blocks
#define SCAN_BLOCKS 256

__device__ __forceinline__ unsigned short f32_to_bf16_rne(float f) {
    unsigned u = __float_as_uint(f);
    unsigned r = u + 0x7FFFu + ((u >> 16) & 1u);
    return (unsigned short)(r >> 16);
}

// ---------------------------------------------------------------------------
__global__ void convert_bf16_kernel(const float* __restrict__ x,
                                    ushort4* __restrict__ xb4, int total4) {
    int i = blockIdx.x * blockDim.x + threadIdx.x;
    if (i >= total4) return;
    float4 v = ((const float4*)x)[i];
    ushort4 o;
    o.x = f32_to_bf16_rne(v.x); o.y = f32_to_bf16_rne(v.y);
    o.z = f32_to_bf16_rne(v.z); o.w = f32_to_bf16_rne(v.w);
    xb4[i] = o;
}

// ---------------------------------------------------------------------------
__global__ __launch_bounds__(256) void bin_count_kernel(
        const int* __restrict__ ei, int* __restrict__ bhistT, int E, int nb) {
    __shared__ int h[NB_HIST_MAX];
    int t = threadIdx.x;
    for (int b = t; b < nb; b += 256) h[b] = 0;
    __syncthreads();
    for (int e = blockIdx.x * 256 + t; e < E; e += BLK1 * 256)
        atomicAdd(&h[ei[E + e] >> BN_SHIFT], 1);
    __syncthreads();
    for (int b = t; b < nb; b += 256)
        bhistT[b * BLK1 + blockIdx.x] = h[b];
}

// --------------------------- 3-pass scan -----------------------------------
__global__ void scan_reduce_kernel(const int* __restrict__ in,
                                   int* __restrict__ bsum, int n, int chunk) {
    __shared__ int ws[4];
    int b = blockIdx.x, t = threadIdx.x;
    int base = b * chunk;
    int lim = min(base + chunk, n);
    int sum = 0;
    for (int i = base + t; i < lim; i += 256) sum += in[i];
    #pragma unroll
    for (int d = 32; d; d >>= 1) sum += __shfl_down(sum, d, 64);
    if ((t & 63) == 0) ws[t >> 6] = sum;
    __syncthreads();
    if (t == 0) bsum[b] = ws[0] + ws[1] + ws[2] + ws[3];
}

__global__ void scan_partials_kernel(const int* __restrict__ bsum,
                                     int* __restrict__ bpre,
                                     int* __restrict__ outp, int n) {
    __shared__ int tmp[SCAN_BLOCKS];
    int t = threadIdx.x;
    int v = bsum[t];
    tmp[t] = v;
    __syncthreads();
    #pragma unroll
    for (int d = 1; d < SCAN_BLOCKS; d <<= 1) {
        int u = (t >= d) ? tmp[t - d] : 0;
        __syncthreads();
        tmp[t] += u;
        __syncthreads();
    }
    bpre[t] = tmp[t] - v;
    if (t == SCAN_BLOCKS - 1) outp[n] = tmp[t];   // total
}

__global__ void scan_write_kernel(const int* __restrict__ in,
                                  const int* __restrict__ bpre,
                                  int* __restrict__ outp, int n, int chunk) {
    __shared__ int tmp[256];
    int b = blockIdx.x, t = threadIdx.x;
    int base = b * chunk;
    int lim = min(base + chunk, n);
    int carry = bpre[b];
    for (int tile = base; tile < lim; tile += 256) {
        int i = tile + t;
        int v = (i < lim) ? in[i] : 0;
        tmp[t] = v;
        __syncthreads();
        #pragma unroll
        for (int d = 1; d < 256; d <<= 1) {
            int u = (t >= d) ? tmp[t - d] : 0;
            __syncthreads();
            tmp[t] += u;
            __syncthreads();
        }
        if (i < lim) outp[i] = carry + (tmp[t] - v);
        int total = tmp[255];
        __syncthreads();
        carry += total;
    }
}

// ---------------------------------------------------------------------------
__global__ __launch_bounds__(256) void bin_scatter_kernel(
        const int* __restrict__ ei, const int* __restrict__ scanT,
        int* __restrict__ binned, int E, int nb) {
    __shared__ int cur[NB_HIST_MAX];
    int t = threadIdx.x;
    for (int b = t; b < nb; b += 256) cur[b] = scanT[b * BLK1 + blockIdx.x];
    __syncthreads();
    for (int e = blockIdx.x * 256 + t; e < E; e += BLK1 * 256) {
        int s = ei[e];
        int d = ei[E + e];
        int p = atomicAdd(&cur[d >> BN_SHIFT], 1);
        binned[p] = (s << BN_SHIFT) | (d & BN_MASK);
    }
}

// ---------------------------------------------------------------------------
// Block per bucket (1024 nodes): counting sort by low-10 dst bits -> CSR.
__global__ __launch_bounds__(256) void bucket_sort_kernel(
        const int* __restrict__ binned, const int* __restrict__ scanT,
        int* __restrict__ srcs, int* __restrict__ offsets, int N, int nb) {
    __shared__ int cnt[BN];      // 4 KB
    __shared__ int basep[BN];    // 4 KB
    __shared__ int tsum[256];
    const int t = threadIdx.x;
    const int b = blockIdx.x;
    const int seg0 = scanT[b * BLK1];
    const int seg1 = scanT[(b + 1) * BLK1];   // b=nb-1 hits scanT[M]=total

    #pragma unroll
    for (int j = t; j < BN; j += 256) cnt[j] = 0;
    __syncthreads();
    for (int i = seg0 + t; i < seg1; i += 256)
        atomicAdd(&cnt[binned[i] & BN_MASK], 1);
    __syncthreads();

    // parallel exclusive prefix over 1024 counters (4 per thread)
    int c0 = cnt[4 * t + 0], c1 = cnt[4 * t + 1];
    int c2 = cnt[4 * t + 2], c3 = cnt[4 * t + 3];
    int s4 = c0 + c1 + c2 + c3;
    tsum[t] = s4;
    __syncthreads();
    #pragma unroll
    for (int d = 1; d < 256; d <<= 1) {
        int u = (t >= d) ? tsum[t - d] : 0;
        __syncthreads();
        tsum[t] += u;
        __syncthreads();
    }
    int excl = tsum[t] - s4;
    basep[4 * t + 0] = excl;
    basep[4 * t + 1] = excl + c0;
    basep[4 * t + 2] = excl + c0 + c1;
    basep[4 * t + 3] = excl + c0 + c1 + c2;
    __syncthreads();

    const int node0 = b << BN_SHIFT;
    #pragma unroll
    for (int j = t; j < BN; j += 256)
        if (node0 + j < N) offsets[node0 + j] = seg0 + basep[j];
    if (b == 0 && t == 0) offsets[N] = scanT[(size_t)nb * BLK1];

    #pragma unroll
    for (int j = t; j < BN; j += 256) cnt[j] = basep[j];  // cursors
    __syncthreads();
    for (int i = seg0 + t; i < seg1; i += 256) {
        int v = binned[i];                    // L2-hot re-read
        int p = atomicAdd(&cnt[v & BN_MASK], 1);
        srcs[seg0 + p] = v >> BN_SHIFT;       // within 64KB window
    }
}

// ---------------------------------------------------------------------------
// bf16 gather: 8 lanes per edge, 16B dwordx4 per lane (8 edges/load inst).
// lane = 8*edge_slot(sub) layout: sub=lane>>3, feature base fb=(lane&7)*8.
__global__ __launch_bounds__(256) void gather_linear_bf16_kernel(
        const unsigned short* __restrict__ xh, const int* __restrict__ offsets,
        const int* __restrict__ srcs, const float* __restrict__ W,
        const float* __restrict__ bias, float* __restrict__ out, int n_nodes) {
    const int lane = threadIdx.x & 63;
    const int sub  = lane >> 3;          // edge slot 0..7
    const int fb   = (lane & 7) << 3;    // feature base 0..56
    const int gwave = (blockIdx.x * blockDim.x + threadIdx.x) >> 6;
    const int total_waves = (gridDim.x * blockDim.x) >> 6;

    float wv[DIM];
    #pragma unroll
    for (int k4 = 0; k4 < DIM / 4; ++k4) {
        float4 tw = *(const float4*)(W + (size_t)lane * DIM + k4 * 4);
        wv[k4 * 4 + 0] = tw.x; wv[k4 * 4 + 1] = tw.y;
        wv[k4 * 4 + 2] = tw.z; wv[k4 * 4 + 3] = tw.w;
    }
    const float bb = bias[lane];

#define BFLO(u) __uint_as_float((u) << 16)
#define BFHI(u) __uint_as_float((u) & 0xFFFF0000u)
#define ACC8(V) do {                                                  \
        a[0] += BFLO((V).x); a[1] += BFHI((V).x);                     \
        a[2] += BFLO((V).y); a[3] += BFHI((V).y);                     \
        a[4] += BFLO((V).z); a[5] += BFHI((V).z);                     \
        a[6] += BFLO((V).w); a[7] += BFHI((V).w); } while (0)

    for (int node = gwave; node < n_nodes; node += total_waves) {
        int beg = offsets[node];
        int end = offsets[node + 1];

        float a[8] = {0.f, 0.f, 0.f, 0.f, 0.f, 0.f, 0.f, 0.f};
        int i = beg;
        for (; i + 16 <= end; i += 16) {          // 2 chunks in flight
            int sA = srcs[i + sub];
            int sB = srcs[i + 8 + sub];
            uint4 vA = *(const uint4*)(xh + (size_t)sA * DIM + fb);
            uint4 vB = *(const uint4*)(xh + (size_t)sB * DIM + fb);
            ACC8(vA);
            ACC8(vB);
        }
        for (; i < end; i += 8) {                 // masked tail chunk
            int idx = i + sub;
            if (idx < end) {
                int s = srcs[idx];
                uint4 v = *(const uint4*)(xh + (size_t)s * DIM + fb);
                ACC8(v);
            }
        }

        // reduce across the 8 edge slots (lanes differing in bits 3..5)
        #pragma unroll
        for (int d = 8; d <= 32; d <<= 1) {
            #pragma unroll
            for (int j = 0; j < 8; ++j) a[j] += __shfl_xor(a[j], d, 64);
        }

        // feature k lives in reg (k&7) of lane (k>>3)
        float r0 = bb, r1 = 0.f, r2 = 0.f, r3 = 0.f;
        #pragma unroll
        for (int k = 0; k < DIM; k += 4) {
            r0 += __int_as_float(__builtin_amdgcn_readlane(
                      __float_as_int(a[(k + 0) & 7]), (k + 0) >> 3)) * wv[k + 0];
            r1 += __int_as_float(__builtin_amdgcn_readlane(
                      __float_as_int(a[(k + 1) & 7]), (k + 1) >> 3)) * wv[k + 1];
            r2 += __int_as_float(__builtin_amdgcn_readlane(
                      __float_as_int(a[(k + 2) & 7]), (k + 2) >> 3)) * wv[k + 2];
            r3 += __int_as_float(__builtin_amdgcn_readlane(
                      __float_as_int(a[(k + 3) & 7]), (k + 3) >> 3)) * wv[k + 3];
        }
        out[(size_t)node * DIM + lane] = (r0 + r1) + (r2 + r3);
    }
#undef BFLO
#undef BFHI
#undef ACC8
}

// ---------------------------------------------------------------------------
// fp32 scalar gather (tiers B/C)
__global__ __launch_bounds__(256) void gather_linear_f32_kernel(
        const float* __restrict__ xf, const int* __restrict__ offsets,
        const int* __restrict__ srcs, const float* __restrict__ W,
        const float* __restrict__ bias, float* __restrict__ out, int n_nodes) {
    const int lane = threadIdx.x & 63;
    const int gwave = (blockIdx.x * blockDim.x + threadIdx.x) >> 6;
    const int total_waves = (gridDim.x * blockDim.x) >> 6;

    float wv[DIM];
    #pragma unroll
    for (int k4 = 0; k4 < DIM / 4; ++k4) {
        float4 tw = *(const float4*)(W + (size_t)lane * DIM + k4 * 4);
        wv[k4 * 4 + 0] = tw.x; wv[k4 * 4 + 1] = tw.y;
        wv[k4 * 4 + 2] = tw.z; wv[k4 * 4 + 3] = tw.w;
    }
    const float b = bias[lane];

    for (int node = gwave; node < n_nodes; node += total_waves) {
        int beg = offsets[node];
        int end = offsets[node + 1];
        float a0 = 0.f, a1 = 0.f, a2 = 0.f, a3 = 0.f;
        int i = beg;
        for (; i + 4 <= end; i += 4) {
            int s0 = srcs[i + 0], s1 = srcs[i + 1];
            int s2 = srcs[i + 2], s3 = srcs[i + 3];
            a0 += xf[(size_t)s0 * DIM + lane];
            a1 += xf[(size_t)s1 * DIM + lane];
            a2 += xf[(size_t)s2 * DIM + lane];
            a3 += xf[(size_t)s3 * DIM + lane];
        }
        for (; i < end; ++i) a0 += xf[(size_t)srcs[i] * DIM + lane];
        float acc = (a0 + a1) + (a2 + a3);

        float r0 = b, r1 = 0.f, r2 = 0.f, r3 = 0.f;
        #pragma unroll
        for (int k = 0; k < DIM; k += 4) {
            r0 += __int_as_float(__builtin_amdgcn_readlane(__float_as_int(acc), k + 0)) * wv[k + 0];
            r1 += __int_as_float(__builtin_amdgcn_readlane(__float_as_int(acc), k + 1)) * wv[k + 1];
            r2 += __int_as_float(__builtin_amdgcn_readlane(__float_as_int(acc), k + 2)) * wv[k + 2];
            r3 += __int_as_float(__builtin_amdgcn_readlane(__float_as_int(acc), k + 3)) * wv[k + 3];
        }
        out[(size_t)node * DIM + lane] = (r0 + r1) + (r2 + r3);
    }
}

// ------------------- tier C: global-atomic CSR build -----------------------
__global__ void hist_kernel(const int* __restrict__ ei, int* __restrict__ counts,
                            int E) {
    int e = blockIdx.x * blockDim.x + threadIdx.x;
    if (e < E) atomicAdd(&counts[ei[E + e]], 1);
}

__global__ void copy_kernel(const int* __restrict__ src, int* __restrict__ dst,
                            int n) {
    int i = blockIdx.x * blockDim.x + threadIdx.x;
    if (i < n) dst[i] = src[i];
}

__global__ void fill_kernel(const int* __restrict__ ei, int* __restrict__ cursor,
                            int* __restrict__ srcs, int E) {
    int e = blockIdx.x * blockDim.x + threadIdx.x;
    if (e < E) {
        int d = ei[E + e];
        int p = atomicAdd(&cursor[d], 1);
        srcs[p] = ei[e];
    }
}

// ------------------- tier D: atomic scatter fallback -----------------------
__global__ void gcn_scatter_kernel(const float* __restrict__ x,
                                   const int* __restrict__ edge_index,
                                   float* __restrict__ out, int n_edges) {
    int gid = blockIdx.x * blockDim.x + threadIdx.x;
    int e = gid >> 4;
    if (e >= n_edges) return;
    int j = (gid & 15) << 2;
    int src = edge_index[e];
    int dst = edge_index[n_edges + e];
    const float4 v = *(const float4*)(x + (size_t)src * DIM + j);
    float* o = out + (size_t)dst * DIM + j;
    atomicAdd(o + 0, v.x); atomicAdd(o + 1, v.y);
    atomicAdd(o + 2, v.z); atomicAdd(o + 3, v.w);
}

__global__ void gcn_linear_inplace_kernel(float* __restrict__ out,
                                          const float* __restrict__ W,
                                          const float* __restrict__ bias,
                                          int n_nodes) {
    __shared__ float Wt[DIM * DIM];
    __shared__ float rows[4][DIM];
    int tid = threadIdx.x;
    int col = tid & 63;
    int r = tid >> 6;
    for (int i = tid; i < DIM * DIM; i += 256) {
        int c = i >> 6, k = i & 63;
        Wt[k * DIM + c] = W[i];
    }
    int row = blockIdx.x * 4 + r;
    if (row < n_nodes) rows[r][col] = out[(size_t)row * DIM + col];
    __syncthreads();
    if (row < n_nodes) {
        float a = 0.f;
        #pragma unroll
        for (int k = 0; k < DIM; ++k) a += rows[r][k] * Wt[k * DIM + col];
        out[(size_t)row * DIM + col] = a + bias[col];
    }
}

// ---------------------------------------------------------------------------
extern "C" void kernel_launch(void* const* d_in, const int* in_sizes, int n_in,
                              void* d_out, int out_size, void* d_ws, size_t ws_size,
                              hipStream_t stream) {
    const float* x          = (const float*)d_in[0];   // [N, 64]
    const float* W          = (const float*)d_in[1];   // [64, 64]
    const float* bias       = (const float*)d_in[2];   // [64]
    const int*   edge_index = (const int*)d_in[3];     // [2, E]

    const int E = in_sizes[3] / 2;
    const int N = in_sizes[0] / DIM;
    float* out = (float*)d_out;

    const int NB = (N + BN - 1) >> BN_SHIFT;
    const long long M = (long long)NB * BLK1;
    const int block = 256;

    auto align256 = [](size_t v) { return (v + 255) & ~(size_t)255; };
    const size_t xb_b   = align256((size_t)N * DIM * 2);
    const size_t bin_b  = align256((size_t)E * 4);
    const size_t hist_b = align256((size_t)M * 4);
    const size_t scan_b = align256(((size_t)M + 1) * 4);
    const size_t srcs_b = align256((size_t)E * 4);
    const size_t offs_b = align256(((size_t)N + 1) * 4);
    const size_t sm_b   = align256(SCAN_BLOCKS * 4);
    const size_t needA = xb_b + bin_b + hist_b + scan_b + srcs_b + offs_b + 2 * sm_b;
    const size_t needC = ((size_t)3 * N + 1 + E + 2 * SCAN_BLOCKS) * sizeof(int);

    if (NB <= NB_HIST_MAX && N <= (1 << 22) && ws_size >= needA) {
        char* p = (char*)d_ws;
        ushort4* xb4 = (ushort4*)p;          p += xb_b;
        int* binned  = (int*)p;              p += bin_b;
        int* bhistT  = (int*)p;              p += hist_b;
        int* scanT   = (int*)p;              p += scan_b;
        int* srcs    = (int*)p;              p += srcs_b;
        int* offsets = (int*)p;              p += offs_b;
        int* bsum    = (int*)p;              p += sm_b;
        int* bpre    = (int*)p;

        const int chunkM = (int)((M + SCAN_BLOCKS - 1) / SCAN_BLOCKS);

        int total4 = N * DIM / 4;
        convert_bf16_kernel<<<(total4 + block - 1) / block, block, 0, stream>>>(
            x, xb4, total4);
        bin_count_kernel<<<BLK1, block, 0, stream>>>(edge_index, bhistT, E, NB);
        scan_reduce_kernel<<<SCAN_BLOCKS, block, 0, stream>>>(bhistT, bsum, (int)M, chunkM);
        scan_partials_kernel<<<1, SCAN_BLOCKS, 0, stream>>>(bsum, bpre, scanT, (int)M);
        scan_write_kernel<<<SCAN_BLOCKS, block, 0, stream>>>(bhistT, bpre, scanT, (int)M, chunkM);
        bin_scatter_kernel<<<BLK1, block, 0, stream>>>(edge_index, scanT, binned, E, NB);
        bucket_sort_kernel<<<NB, block, 0, stream>>>(binned, scanT, srcs, offsets, N, NB);

        int waves = (N + 7) / 8;
        int ggrid = (waves + 3) / 4;
        gather_linear_bf16_kernel<<<ggrid, block, 0, stream>>>(
            (const unsigned short*)xb4, offsets, srcs, W, bias, out, N);
    } else if (ws_size >= needC) {
        int* counts  = (int*)d_ws;
        int* offsets = counts + N;
        int* cursor  = offsets + N + 1;
        int* srcs    = cursor + N;
        int* bsum    = srcs + E;
        int* bpre    = bsum + SCAN_BLOCKS;

        hipMemsetAsync(counts, 0, (size_t)N * sizeof(int), stream);
        const int egrid = (E + block - 1) / block;
        const int chunkN = (N + SCAN_BLOCKS - 1) / SCAN_BLOCKS;
        hist_kernel<<<egrid, block, 0, stream>>>(edge_index, counts, E);
        scan_reduce_kernel<<<SCAN_BLOCKS, block, 0, stream>>>(counts, bsum, N, chunkN);
        scan_partials_kernel<<<1, SCAN_BLOCKS, 0, stream>>>(bsum, bpre, offsets, N);
        scan_write_kernel<<<SCAN_BLOCKS, block, 0, stream>>>(counts, bpre, offsets, N, chunkN);
        copy_kernel<<<(N + block - 1) / block, block, 0, stream>>>(offsets, cursor, N);
        fill_kernel<<<egrid, block, 0, stream>>>(edge_index, cursor, srcs, E);
        int waves = (N + 7) / 8;
        int ggrid = (waves + 3) / 4;
        gather_linear_f32_kernel<<<ggrid, block, 0, stream>>>(
            x, offsets, srcs, W, bias, out, N);
    } else {
        hipMemsetAsync(d_out, 0, (size_t)out_size * sizeof(float), stream);
        long long total = (long long)E * 16;
        int grid = (int)((total + block - 1) / block);
        gcn_scatter_kernel<<<grid, block, 0, stream>>>(x, edge_index, out, E);
        int lgrid = (N + 3) / 4;
        gcn_linear_inplace_kernel<<<lgrid, 256, 0, stream>>>(out, W, bias, N);
    }
}